// Round 16
// baseline (42.171 us; speedup 1.0000x reference)
//
#include <hip/hip_runtime.h>
#include <hip/hip_bf16.h>

#define TOKENS    16384      // B*N = 4*4096
#define DIM       2048
#define NEXP      8
#define NBATCH    4
#define TOK_PER_B 4096
#define ALPHA     0.1f
#define NBLK      512        // 512-thread blocks, 8 waves, 32 tokens each, 2/CU
#define TPB       32
#define NWAVE     8
#define CHUNK     256        // dims per chunk (64 float4)
#define NCHUNK    8

typedef const __attribute__((address_space(1))) unsigned int* gas_t;
typedef __attribute__((address_space(3))) unsigned int* las_t;

// ws layout: per block 16 floats: [0..7] score sums, [8..15] top-k counts.

__device__ __forceinline__ float dot4(float4 a, float4 b) {
    return a.x * b.x + a.y * b.y + a.z * b.z + a.w * b.w;
}

// R15 compute verbatim; scheduling fixes: (1) chunk-0 x loads issued BEFORE the
// W-DMA wait (vmcnt(8) leaves them in flight -> prologue overlap), (2) 512x512
// launch -> 2 blocks/CU, narrower barrier, finer dispatch tail.
__global__ __launch_bounds__(512, 2)
void gate_kernel(const float* __restrict__ x, const float* __restrict__ W,
                 float* __restrict__ out, float* __restrict__ ws)
{
    __shared__ float Wl[NEXP * DIM];          // 64 KiB
    __shared__ float s_part[NWAVE][NEXP];
    __shared__ float s_pcnt[NWAVE][NEXP];

    const int tid  = threadIdx.x;
    const int lane = tid & 63;
    const int wavu = __builtin_amdgcn_readfirstlane(tid >> 6);  // 0..7, uniform
    const int tok0 = blockIdx.x * TPB + wavu * 4;               // wave's 4 tokens

    const float4* xr = (const float4*)(x + (size_t)tok0 * DIM); // row t: +t*512

    // W -> LDS via DMA (8 size-16 per wave = 64 KiB block-wide).
    #pragma unroll
    for (int i = 0; i < 8; ++i)
        __builtin_amdgcn_global_load_lds((gas_t)(W + wavu * 2048 + i * 256 + lane * 4),
                                         (las_t)(Wl + wavu * 2048 + i * 256), 16, 0, 0);

    // Issue chunk-0 x loads NOW (they ride behind the DMAs; vmcnt(4) below
    // waits only for the 8 W-DMAs, leaving these 4 in flight).
    float4 xc[4], xn[4];
    #pragma unroll
    for (int t = 0; t < 4; ++t) xc[t] = xr[t * (DIM / 4) + lane];

    asm volatile("s_waitcnt vmcnt(4)" ::: "memory");   // W landed; x still flying
    __builtin_amdgcn_sched_barrier(0);
    __syncthreads();                                   // everyone's W visible

    const float4* Wl4 = (const float4*)Wl;

    float acc[4][NEXP];
    #pragma unroll
    for (int t = 0; t < 4; ++t)
        #pragma unroll
        for (int e = 0; e < NEXP; ++e) acc[t][e] = 0.f;

    #pragma unroll 1
    for (int c = 0; c < NCHUNK; ++c) {
        if (c < NCHUNK - 1) {   // prefetch next chunk: 4 coalesced 1 KiB loads
            #pragma unroll
            for (int t = 0; t < 4; ++t)
                xn[t] = xr[t * (DIM / 4) + (c + 1) * 64 + lane];
        }
        #pragma unroll
        for (int e = 0; e < NEXP; e += 2) {
            float4 w0 = Wl4[(e    ) * (DIM / 4) + c * 64 + lane];  // b128, conflict-free
            float4 w1 = Wl4[(e + 1) * (DIM / 4) + c * 64 + lane];
            #pragma unroll
            for (int t = 0; t < 4; ++t) {
                acc[t][e]     += dot4(xc[t], w0);
                acc[t][e + 1] += dot4(xc[t], w1);
            }
        }
        if (c < NCHUNK - 1) {
            #pragma unroll
            for (int t = 0; t < 4; ++t) xc[t] = xn[t];
        }
    }

    // ---- Fold + token-parallel softmax/top-2/aux (verbatim R7/R11, verified) ----
    const bool b0 = lane & 1;
    const bool b1 = lane & 2;
    const bool b2 = lane & 4;
    const bool b4 = lane & 16;
    const bool b5 = lane & 32;
    const int  myexp = lane & 7;
    const int  grp8  = (lane >> 3) * 8;
    const int  myj   = ((lane >> 4) & 1) * 2 + ((lane >> 5) & 1);

    float r[4];
    #pragma unroll
    for (int j = 0; j < 4; ++j) {
        float m0 = b0 ? acc[j][1] : acc[j][0], s0 = b0 ? acc[j][0] : acc[j][1];
        float m1 = b0 ? acc[j][3] : acc[j][2], s1 = b0 ? acc[j][2] : acc[j][3];
        float m2 = b0 ? acc[j][5] : acc[j][4], s2 = b0 ? acc[j][4] : acc[j][5];
        float m3 = b0 ? acc[j][7] : acc[j][6], s3 = b0 ? acc[j][6] : acc[j][7];
        float k0 = m0 + __shfl_xor(s0, 1, 64);
        float k1 = m1 + __shfl_xor(s1, 1, 64);
        float k2 = m2 + __shfl_xor(s2, 1, 64);
        float k3 = m3 + __shfl_xor(s3, 1, 64);
        float n0 = b1 ? k1 : k0, q0 = b1 ? k0 : k1;
        float n1 = b1 ? k3 : k2, q1 = b1 ? k2 : k3;
        float h0 = n0 + __shfl_xor(q0, 2, 64);
        float h1 = n1 + __shfl_xor(q1, 2, 64);
        float nm = b2 ? h1 : h0, nq = b2 ? h0 : h1;
        float rj = nm + __shfl_xor(nq, 4, 64);
        r[j] = rj + __shfl_xor(rj, 8, 64);
    }
    float a_  = b4 ? r[2] : r[0], as_ = b4 ? r[0] : r[2];
    float bb  = b4 ? r[3] : r[1], bs_ = b4 ? r[1] : r[3];
    a_ += __shfl_xor(as_, 16, 64);
    bb += __shfl_xor(bs_, 16, 64);
    float sel = b5 ? bb : a_, snd = b5 ? a_ : bb;
    float rr  = sel + __shfl_xor(snd, 32, 64);

    float m = rr;
    m = fmaxf(m, __shfl_xor(m, 1, 64));
    m = fmaxf(m, __shfl_xor(m, 2, 64));
    m = fmaxf(m, __shfl_xor(m, 4, 64));
    float p = __expf(rr - m);
    float s = p;
    s += __shfl_xor(s, 1, 64);
    s += __shfl_xor(s, 2, 64);
    s += __shfl_xor(s, 4, 64);
    float inv = 1.0f / s;

    unsigned long long bm = __ballot(rr == m);
    int i0 = __ffs((unsigned)((bm >> grp8) & 0xffULL)) - 1;   // jax tie-break
    float rm = (myexp == i0) ? -3.4e38f : rr;
    float mm = rm;
    mm = fmaxf(mm, __shfl_xor(mm, 1, 64));
    mm = fmaxf(mm, __shfl_xor(mm, 2, 64));
    mm = fmaxf(mm, __shfl_xor(mm, 4, 64));
    unsigned long long bm2 = __ballot(rm == mm);
    int i1 = __ffs((unsigned)((bm2 >> grp8) & 0xffULL)) - 1;

    float v0 = inv;
    float v1 = __expf(mm - m) * inv;

    float pacc = (lane & 8) ? 0.f : p * inv;
    float cacc = (lane & 8) ? 0.f : ((myexp == i0 ? 1.f : 0.f) + (myexp == i1 ? 1.f : 0.f));
    pacc += __shfl_xor(pacc, 8, 64);
    pacc += __shfl_xor(pacc, 16, 64);
    pacc += __shfl_xor(pacc, 32, 64);
    cacc += __shfl_xor(cacc, 8, 64);
    cacc += __shfl_xor(cacc, 16, 64);
    cacc += __shfl_xor(cacc, 32, 64);

    if ((lane & 15) == 0) {               // one writer per token quadrant
        const int t = tok0 + myj;
        out[(size_t)t * 2 + 0] = v0;
        out[(size_t)t * 2 + 1] = v1;
        out[(size_t)TOKENS * 2 + (size_t)t * 2 + 0] = (float)i0;
        out[(size_t)TOKENS * 2 + (size_t)t * 2 + 1] = (float)i1;
    }

    if (lane < NEXP) {
        s_part[wavu][lane] = pacc;
        s_pcnt[wavu][lane] = cacc;
    }
    __syncthreads();
    if (tid < NEXP) {
        float sp = 0.f, sc = 0.f;
        #pragma unroll
        for (int w = 0; w < NWAVE; ++w) { sp += s_part[w][tid]; sc += s_pcnt[w][tid]; }
        ws[blockIdx.x * 16 + tid]     = sp;
        ws[blockIdx.x * 16 + 8 + tid] = sc;
    }
}

// 512 blocks x 16 floats in ws; 128 blocks per batch (R8 finalize, verified).
__global__ void finalize_kernel(const float* __restrict__ ws, float* __restrict__ out)
{
    __shared__ float red[256];
    __shared__ float fin[64];
    const int tid  = threadIdx.x;       // 256 threads
    const int cell = tid >> 2;          // 0..63 : b*16 + c
    const int q    = tid & 3;
    const int b    = cell >> 4;
    const int c    = cell & 15;

    float acc = 0.f;
    #pragma unroll
    for (int k = 0; k < 32; ++k)        // 32 independent loads in flight
        acc += ws[(size_t)(b * 128 + q + k * 4) * 16 + c];
    red[cell * 4 + q] = acc;
    __syncthreads();

    if (tid < 64)
        fin[tid] = red[tid * 4] + red[tid * 4 + 1] + red[tid * 4 + 2] + red[tid * 4 + 3];
    __syncthreads();

    if (tid == 0) {
        float aux = 0.f;
        for (int bb = 0; bb < NBATCH; ++bb) {
            float a2 = 0.f;
            for (int e = 0; e < NEXP; ++e) {
                float pi = fin[bb * 16 + e] * (1.f / TOK_PER_B);
                float fi = fin[bb * 16 + 8 + e] * ((float)NEXP / (2.f * TOK_PER_B));
                a2 += fi * pi;
            }
            aux += a2;
        }
        out[(size_t)TOKENS * 4] = aux * (1.f / NBATCH) * ALPHA;  // out[65536]
    }
}

extern "C" void kernel_launch(void* const* d_in, const int* in_sizes, int n_in,
                              void* d_out, int out_size, void* d_ws, size_t ws_size,
                              hipStream_t stream) {
    const float* x = (const float*)d_in[0];
    const float* W = (const float*)d_in[1];
    float* out = (float*)d_out;
    float* ws  = (float*)d_ws;

    gate_kernel<<<dim3(NBLK), dim3(512), 0, stream>>>(x, W, out, ws);
    finalize_kernel<<<1, 256, 0, stream>>>(ws, out);
}

// Round 17
// 31.387 us; speedup vs baseline: 1.3436x; 1.3436x over previous
//
#include <hip/hip_runtime.h>
#include <hip/hip_bf16.h>

#define TOKENS    16384      // B*N = 4*4096
#define DIM       2048
#define NEXP      8
#define NBATCH    4
#define TOK_PER_B 4096
#define ALPHA     0.1f
#define NBLK      256        // 1024-thread blocks, 64 tokens each, 1/CU
#define TPB       64
#define CHUNK     128        // dims per chunk
#define NCHUNK    16

typedef const __attribute__((address_space(1))) unsigned int* gas_t;
typedef __attribute__((address_space(3))) unsigned int* las_t;

// ws layout: per block 16 floats: [0..7] score sums, [8..15] top-k counts.

// R11 verbatim (best measured: 31.5us). Wave-autonomous streaming: wave w owns
// tokens [blk*64 + w*4, +4). Per chunk it DMAs its own 2KB x-slice (2 size-16
// global_load_lds, contiguous 1KB each), waits counted vmcnt(2) (next chunk
// stays in flight -- no drain), computes float2/lane partial dots vs W in LDS.
// NO barriers in the main loop. Two dispatches (fusion measured worse, R13/R14).
__global__ __launch_bounds__(1024, 1)
void gate_kernel(const float* __restrict__ x, const float* __restrict__ W,
                 float* __restrict__ out, float* __restrict__ ws)
{
    __shared__ float Wl[NEXP * DIM];          // 64 KiB
    __shared__ float xs[2][16][4 * CHUNK];    // 64 KiB: [buf][wave][tok*128+d]
    __shared__ float s_part[16][NEXP];
    __shared__ float s_pcnt[16][NEXP];

    const int tid  = threadIdx.x;
    const int lane = tid & 63;
    const int wavu = __builtin_amdgcn_readfirstlane(tid >> 6);  // 0..15, uniform
    const int tok0 = blockIdx.x * TPB + wavu * 4;               // wave's 4 tokens

    // ---- W DMA first (4 per wave, 64KB total), then x chunk 0 (2 per wave) ----
    #pragma unroll
    for (int i = 0; i < 4; ++i) {
        const float* src = W + wavu * 1024 + i * 256 + lane * 4;
        __builtin_amdgcn_global_load_lds((gas_t)src,
                                         (las_t)(Wl + wavu * 1024 + i * 256), 16, 0, 0);
    }
    {   // stage chunk 0 into buf 0
        const float* srow = x + (size_t)tok0 * DIM + 0 * CHUNK;
        #pragma unroll
        for (int d = 0; d < 2; ++d)
            __builtin_amdgcn_global_load_lds(
                (gas_t)(srow + (size_t)(2 * d + (lane >> 5)) * DIM + (lane & 31) * 4),
                (las_t)(&xs[0][wavu][0] + d * 256), 16, 0, 0);
    }
    asm volatile("s_waitcnt vmcnt(2)" ::: "memory");  // oldest 4 = W landed
    __builtin_amdgcn_sched_barrier(0);
    __syncthreads();                                   // everyone's W visible

    float acc[4][NEXP];
    #pragma unroll
    for (int t = 0; t < 4; ++t)
        #pragma unroll
        for (int e = 0; e < NEXP; ++e) acc[t][e] = 0.f;

    #pragma unroll 1
    for (int c = 0; c < NCHUNK; ++c) {
        const int cb = c & 1;
        if (c < NCHUNK - 1) {   // issue next chunk, then wait ONLY for current
            const float* srow = x + (size_t)tok0 * DIM + (c + 1) * CHUNK;
            #pragma unroll
            for (int d = 0; d < 2; ++d)
                __builtin_amdgcn_global_load_lds(
                    (gas_t)(srow + (size_t)(2 * d + (lane >> 5)) * DIM + (lane & 31) * 4),
                    (las_t)(&xs[cb ^ 1][wavu][0] + d * 256), 16, 0, 0);
            asm volatile("s_waitcnt vmcnt(2)" ::: "memory");  // chunk c landed
        } else {
            asm volatile("s_waitcnt vmcnt(0)" ::: "memory");
        }
        __builtin_amdgcn_sched_barrier(0);

        const float* xsl = &xs[cb][wavu][0];
        float2 xv[4];
        #pragma unroll
        for (int t = 0; t < 4; ++t)
            xv[t] = *(const float2*)&xsl[t * CHUNK + lane * 2];  // consecutive-lane
        #pragma unroll
        for (int e = 0; e < NEXP; e += 2) {
            float2 w0 = *(const float2*)&Wl[(e    ) * DIM + c * CHUNK + lane * 2];
            float2 w1 = *(const float2*)&Wl[(e + 1) * DIM + c * CHUNK + lane * 2];
            #pragma unroll
            for (int t = 0; t < 4; ++t) {
                acc[t][e]     += xv[t].x * w0.x + xv[t].y * w0.y;
                acc[t][e + 1] += xv[t].x * w1.x + xv[t].y * w1.y;
            }
        }
    }

    // ---- Fold + token-parallel softmax/top-2/aux (verbatim R7, verified) ----
    const bool b0 = lane & 1;
    const bool b1 = lane & 2;
    const bool b2 = lane & 4;
    const bool b4 = lane & 16;
    const bool b5 = lane & 32;
    const int  myexp = lane & 7;
    const int  grp8  = (lane >> 3) * 8;
    const int  myj   = ((lane >> 4) & 1) * 2 + ((lane >> 5) & 1);

    float r[4];
    #pragma unroll
    for (int j = 0; j < 4; ++j) {
        float m0 = b0 ? acc[j][1] : acc[j][0], s0 = b0 ? acc[j][0] : acc[j][1];
        float m1 = b0 ? acc[j][3] : acc[j][2], s1 = b0 ? acc[j][2] : acc[j][3];
        float m2 = b0 ? acc[j][5] : acc[j][4], s2 = b0 ? acc[j][4] : acc[j][5];
        float m3 = b0 ? acc[j][7] : acc[j][6], s3 = b0 ? acc[j][6] : acc[j][7];
        float k0 = m0 + __shfl_xor(s0, 1, 64);
        float k1 = m1 + __shfl_xor(s1, 1, 64);
        float k2 = m2 + __shfl_xor(s2, 1, 64);
        float k3 = m3 + __shfl_xor(s3, 1, 64);
        float n0 = b1 ? k1 : k0, q0 = b1 ? k0 : k1;
        float n1 = b1 ? k3 : k2, q1 = b1 ? k2 : k3;
        float h0 = n0 + __shfl_xor(q0, 2, 64);
        float h1 = n1 + __shfl_xor(q1, 2, 64);
        float nm = b2 ? h1 : h0, nq = b2 ? h0 : h1;
        float rj = nm + __shfl_xor(nq, 4, 64);
        r[j] = rj + __shfl_xor(rj, 8, 64);
    }
    float a_  = b4 ? r[2] : r[0], as_ = b4 ? r[0] : r[2];
    float bb  = b4 ? r[3] : r[1], bs_ = b4 ? r[1] : r[3];
    a_ += __shfl_xor(as_, 16, 64);
    bb += __shfl_xor(bs_, 16, 64);
    float sel = b5 ? bb : a_, snd = b5 ? a_ : bb;
    float rr  = sel + __shfl_xor(snd, 32, 64);

    float m = rr;
    m = fmaxf(m, __shfl_xor(m, 1, 64));
    m = fmaxf(m, __shfl_xor(m, 2, 64));
    m = fmaxf(m, __shfl_xor(m, 4, 64));
    float p = __expf(rr - m);
    float s = p;
    s += __shfl_xor(s, 1, 64);
    s += __shfl_xor(s, 2, 64);
    s += __shfl_xor(s, 4, 64);
    float inv = 1.0f / s;

    unsigned long long bm = __ballot(rr == m);
    int i0 = __ffs((unsigned)((bm >> grp8) & 0xffULL)) - 1;   // jax tie-break
    float rm = (myexp == i0) ? -3.4e38f : rr;
    float mm = rm;
    mm = fmaxf(mm, __shfl_xor(mm, 1, 64));
    mm = fmaxf(mm, __shfl_xor(mm, 2, 64));
    mm = fmaxf(mm, __shfl_xor(mm, 4, 64));
    unsigned long long bm2 = __ballot(rm == mm);
    int i1 = __ffs((unsigned)((bm2 >> grp8) & 0xffULL)) - 1;

    float v0 = inv;
    float v1 = __expf(mm - m) * inv;

    float pacc = (lane & 8) ? 0.f : p * inv;
    float cacc = (lane & 8) ? 0.f : ((myexp == i0 ? 1.f : 0.f) + (myexp == i1 ? 1.f : 0.f));
    pacc += __shfl_xor(pacc, 8, 64);
    pacc += __shfl_xor(pacc, 16, 64);
    pacc += __shfl_xor(pacc, 32, 64);
    cacc += __shfl_xor(cacc, 8, 64);
    cacc += __shfl_xor(cacc, 16, 64);
    cacc += __shfl_xor(cacc, 32, 64);

    if ((lane & 15) == 0) {               // one writer per token quadrant
        const int t = tok0 + myj;
        out[(size_t)t * 2 + 0] = v0;
        out[(size_t)t * 2 + 1] = v1;
        out[(size_t)TOKENS * 2 + (size_t)t * 2 + 0] = (float)i0;
        out[(size_t)TOKENS * 2 + (size_t)t * 2 + 1] = (float)i1;
    }

    if (lane < NEXP) {
        s_part[wavu][lane] = pacc;
        s_pcnt[wavu][lane] = cacc;
    }
    __syncthreads();
    if (tid < NEXP) {
        float sp = 0.f, sc = 0.f;
        #pragma unroll
        for (int w = 0; w < 16; ++w) { sp += s_part[w][tid]; sc += s_pcnt[w][tid]; }
        ws[blockIdx.x * 16 + tid]     = sp;
        ws[blockIdx.x * 16 + 8 + tid] = sc;
    }
}

// 256 blocks x 16 floats in ws; 64 blocks per batch.
__global__ void finalize_kernel(const float* __restrict__ ws, float* __restrict__ out)
{
    __shared__ float red[256];
    __shared__ float fin[64];
    const int tid  = threadIdx.x;       // 256 threads
    const int cell = tid >> 2;          // 0..63 : b*16 + c
    const int q    = tid & 3;
    const int b    = cell >> 4;
    const int c    = cell & 15;

    float acc = 0.f;
    #pragma unroll
    for (int k = 0; k < 16; ++k)        // 16 independent loads in flight
        acc += ws[(size_t)(b * 64 + q + k * 4) * 16 + c];
    red[cell * 4 + q] = acc;
    __syncthreads();

    if (tid < 64)
        fin[tid] = red[tid * 4] + red[tid * 4 + 1] + red[tid * 4 + 2] + red[tid * 4 + 3];
    __syncthreads();

    if (tid == 0) {
        float aux = 0.f;
        for (int bb = 0; bb < NBATCH; ++bb) {
            float a2 = 0.f;
            for (int e = 0; e < NEXP; ++e) {
                float pi = fin[bb * 16 + e] * (1.f / TOK_PER_B);
                float fi = fin[bb * 16 + 8 + e] * ((float)NEXP / (2.f * TOK_PER_B));
                a2 += fi * pi;
            }
            aux += a2;
        }
        out[(size_t)TOKENS * 4] = aux * (1.f / NBATCH) * ALPHA;  // out[65536]
    }
}

extern "C" void kernel_launch(void* const* d_in, const int* in_sizes, int n_in,
                              void* d_out, int out_size, void* d_ws, size_t ws_size,
                              hipStream_t stream) {
    const float* x = (const float*)d_in[0];
    const float* W = (const float*)d_in[1];
    float* out = (float*)d_out;
    float* ws  = (float*)d_ws;

    gate_kernel<<<dim3(NBLK), dim3(1024), 0, stream>>>(x, W, out, ws);
    finalize_kernel<<<1, 256, 0, stream>>>(ws, out);
}